// Round 15
// baseline (394.790 us; speedup 1.0000x reference)
//
#include <hip/hip_runtime.h>
#include <hip/hip_bf16.h>

typedef __attribute__((ext_vector_type(8))) __bf16 bf16x8;
typedef __attribute__((ext_vector_type(8))) unsigned short ushort8;
typedef __attribute__((ext_vector_type(4))) float f32x4;
typedef __attribute__((ext_vector_type(4))) unsigned uint4v;

__device__ __forceinline__ unsigned short f2bf(float f){
  union { float f; unsigned u; } v; v.f = f;
  unsigned r = v.u + 0x7fffu + ((v.u >> 16) & 1u);
  return (unsigned short)(r >> 16);
}

// non-rematerializable 16B load, SELF-WAITING: result is architecturally valid
// immediately after the asm block, so allocator spills (if any) store valid data.
// (R14 lesson: separate deferred s_waitcnt + spill-after-asm => undefined regs.)
__device__ __forceinline__ f32x4 gload16(const unsigned short* p){
  f32x4 r;
  asm volatile("global_load_dwordx4 %0, %1, off\n\ts_waitcnt vmcnt(0)"
               : "=v"(r) : "v"(p) : "memory");
  return r;
}

// Weight transpose+convert with per-32-col even/odd interleave:
// logical col n -> storage row nn = (n/32)*32 + (n&1)*16 + ((n%32)>>1)
// Wave wv owns logical cols [32wv,32wv+32): frag0 = storage rows [32wv,32wv+16) = even
// cols, frag1 = odd cols; lane lr's pair = logical cols (32wv+2lr, 32wv+2lr+1).
__global__ void prep_weights(const float* __restrict__ W0, const float* __restrict__ W1,
                             unsigned short* __restrict__ wst0, unsigned short* __restrict__ wst1){
  int idx = blockIdx.x * 256 + threadIdx.x;
  if (idx < 256*128){
    int k = idx >> 7, n = idx & 127;
    int nn = (n >> 5) * 32 + (n & 1) * 16 + ((n & 31) >> 1);
    wst0[nn*256 + k] = f2bf(W0[idx]);
  } else if (idx < 256*128 + 128*128){
    int j = idx - 256*128;
    int k = j >> 7, n = j & 127;
    int nn = (n >> 5) * 32 + (n & 1) * 16 + ((n & 31) >> 1);
    wst1[nn*128 + k] = f2bf(W1[j]);
  }
}

__global__ void conv_bf16(const float* __restrict__ src, unsigned short* __restrict__ dst, int n8){
  int i = blockIdx.x * 256 + threadIdx.x;
  if (i < n8){
    const float4* s = (const float4*)src + (size_t)i * 2;
    float4 a = s[0], b = s[1];
    ushort8 p;
    p[0]=f2bf(a.x); p[1]=f2bf(a.y); p[2]=f2bf(a.z); p[3]=f2bf(a.w);
    p[4]=f2bf(b.x); p[5]=f2bf(b.y); p[6]=f2bf(b.z); p[7]=f2bf(b.w);
    *(ushort8*)(dst + (size_t)i * 8) = p;
  }
}

#define SBAR() __builtin_amdgcn_sched_barrier(0)

// 4 waves x 32 output cols (even/odd paired); 64 edges/tile; LDS 49152 -> 3 blocks/CU.
// Halves per-tile LDS A-reads vs the 8-wave layout (A-data read by 4 waves not 8).
//   zA:    [0,32768)      128 half-rows x 256B, chunk ^ (edge&15) (source-side swizzle)
//   h0/pd: [32768,49152)  64 rows x 256B bf16 (logical col order), byte ^ ((row&15)<<4)
//          time-shared: h0 lives L0->L1; pd overwrites after h0-free barrier;
//          epilogue(t) deferred into t+1's L0 phase (loop-top full drain = pd ready).
template<bool TAB16>
__global__ __launch_bounds__(256, 3) void edge_mlp(
    const float* __restrict__ zu, const float* __restrict__ zm,
    const unsigned short* __restrict__ zub, const unsigned short* __restrict__ zmb,
    const int* __restrict__ row, const int* __restrict__ col,
    const unsigned short* __restrict__ wst0, const unsigned short* __restrict__ wst1,
    const float* __restrict__ b0, const float* __restrict__ b1,
    const float* __restrict__ W2, const float* __restrict__ b2v,
    float* __restrict__ out, int E, int ntiles)
{
  __shared__ unsigned char smem[49152];
  const unsigned HOFF = 32768;

  const int tid = threadIdx.x;
  const int wv = tid >> 6, lane = tid & 63;
  const int lr = lane & 15, lk = lane >> 4;
  const int cbase = wv * 32;                  // this wave's 32 logical cols
  const unsigned xl = (unsigned)(lr << 4);    // 4-bit read swizzle

  const float2 b0p = *(const float2*)(b0 + cbase + 2*lr);
  const float2 b1p = *(const float2*)(b1 + cbase + 2*lr);
  const float2 w2p = *(const float2*)(W2 + cbase + 2*lr);
  const float b2s = b2v[0];

  // per-wave weights: 24 frags = 96 VGPRs, self-waiting asm loads
  f32x4 wf0[8][2], wf1[4][2];
  #pragma unroll
  for (int ks = 0; ks < 8; ++ks){
    wf0[ks][0] = gload16(wst0 + (cbase + lr) * 256 + ks*32 + lk*8);
    wf0[ks][1] = gload16(wst0 + (cbase + 16 + lr) * 256 + ks*32 + lk*8);
  }
  #pragma unroll
  for (int ks = 0; ks < 4; ++ks){
    wf1[ks][0] = gload16(wst1 + (cbase + lr) * 128 + ks*32 + lk*8);
    wf1[ks][1] = gload16(wst1 + (cbase + 16 + lr) * 128 + ks*32 + lk*8);
  }

  int idxs[8];
  auto load_idx = [&](int tt){
    #pragma unroll
    for (int p = 0; p < 8; ++p){
      int H = p*16 + wv*4 + lk;              // half-row 0..127
      int e = tt*64 + (H >> 1); if (e >= E) e = E - 1;
      idxs[p] = (H & 1) ? col[e] : row[e];
    }
  };
  auto issue_gather = [&](){                 // direct-to-LDS, source-side 4-bit swizzle
    #pragma unroll
    for (int p = 0; p < 8; ++p){
      int H = p*16 + wv*4 + lk;
      int rl = H >> 1;                       // edge index
      const unsigned short* src = ((H & 1) ? zmb : zub)
          + (size_t)idxs[p] * 128 + ((lr ^ (rl & 15)) << 3);
      __builtin_amdgcn_global_load_lds(
          (const __attribute__((address_space(1))) unsigned*)src,
          (__attribute__((address_space(3))) unsigned*)(&smem[(unsigned)(p*16 + wv*4) * 256]),
          16, 0, 0);
    }
  };
  auto gather_f32 = [&](){                   // fallback: reg-staged convert + swizzled ds_write
    #pragma unroll
    for (int p = 0; p < 8; ++p){
      int H = p*16 + wv*4 + lk;
      int rl = H >> 1;
      const float* s = ((H & 1) ? zm : zu) + (size_t)idxs[p] * 128 + lr*8;
      float4 a = *(const float4*)s, b = *(const float4*)(s + 4);
      ushort8 pck;
      pck[0]=f2bf(a.x); pck[1]=f2bf(a.y); pck[2]=f2bf(a.z); pck[3]=f2bf(a.w);
      pck[4]=f2bf(b.x); pck[5]=f2bf(b.y); pck[6]=f2bf(b.z); pck[7]=f2bf(b.w);
      *(ushort8*)&smem[(unsigned)H * 256 + ((unsigned)(lr ^ (rl & 15)) << 4)] = pck;
    }
  };
  auto epilogue = [&](int tt){               // sum pd rows (order-invariant), 64 lanes
    if (tid < 64){
      float s = b2s;
      const unsigned rx = (unsigned)((tid & 15) << 4);
      #pragma unroll
      for (int c = 0; c < 16; ++c){
        uint4v u = *(const uint4v*)&smem[HOFF + (unsigned)tid*256 + (((unsigned)(c*16)) ^ rx)];
        #pragma unroll
        for (int j = 0; j < 4; ++j){
          union { unsigned u; float f; } lo, hi;
          lo.u = u[j] << 16; hi.u = u[j] & 0xFFFF0000u;
          s += lo.f + hi.f;
        }
      }
      int e = tt*64 + tid;
      if (e < E) out[e] = s;
    }
  };

  int t = blockIdx.x;
  int tprev = -1;
  load_idx(t);
  if constexpr (TAB16) issue_gather(); else gather_f32();

  for (; t < ntiles; t += gridDim.x){
    const int tn = t + gridDim.x;
    const bool pref = tn < ntiles;

    // (1) gather(t) ready AND pd(tprev) ready (full drain covers both)
    SBAR(); asm volatile("s_waitcnt vmcnt(0) lgkmcnt(0)" ::: "memory");
    __builtin_amdgcn_s_barrier(); SBAR();

    if (tprev >= 0) epilogue(tprev);         // hides under L0 phase
    if (pref) load_idx(tn);                  // index prefetch under L0

    // ---- layer 0: zA[64,256] x W0 (32 cols as even/odd frag pair) ----
    f32x4 acc[4][2];
    #pragma unroll
    for (int mt = 0; mt < 4; ++mt){ acc[mt][0] = (f32x4)(b0p.x); acc[mt][1] = (f32x4)(b0p.y); }
    #pragma unroll
    for (int ks = 0; ks < 8; ++ks){
      const unsigned cb = (unsigned)(ks*64 + lk*16);
      #pragma unroll
      for (int mt = 0; mt < 4; ++mt){
        bf16x8 a = *(const bf16x8*)&smem[(unsigned)(mt*16 + lr) * 512 + (cb ^ xl)];
        acc[mt][0] = __builtin_amdgcn_mfma_f32_16x16x32_bf16(a, __builtin_bit_cast(bf16x8, wf0[ks][0]), acc[mt][0], 0, 0, 0);
        acc[mt][1] = __builtin_amdgcn_mfma_f32_16x16x32_bf16(a, __builtin_bit_cast(bf16x8, wf0[ks][1]), acc[mt][1], 0, 0, 0);
      }
    }

    // (2) zA free (and epilogue reads done before h0-write overwrites region)
    SBAR(); asm volatile("s_waitcnt lgkmcnt(0)" ::: "memory");
    __builtin_amdgcn_s_barrier(); SBAR();

    if (pref){ if constexpr (TAB16) issue_gather(); else gather_f32(); }  // flies to next loop-top

    // h0 = relu(acc) -> LDS, paired cols -> one b32 write per (mt,r); 2-way max
    #pragma unroll
    for (int mt = 0; mt < 4; ++mt){
      #pragma unroll
      for (int r = 0; r < 4; ++r){
        float v0 = acc[mt][0][r]; v0 = v0 > 0.f ? v0 : 0.f;
        float v1 = acc[mt][1][r]; v1 = v1 > 0.f ? v1 : 0.f;
        unsigned pk;
        asm("v_cvt_pk_bf16_f32 %0, %1, %2" : "=v"(pk) : "v"(v0), "v"(v1));
        int rr = mt*16 + lk*4 + r;
        *(unsigned*)&smem[HOFF + (unsigned)rr*256 +
            (((unsigned)(cbase*2 + 4*lr)) ^ ((unsigned)((rr & 15) << 4)))] = pk;
      }
    }

    // (3) h0 ready
    SBAR(); asm volatile("s_waitcnt lgkmcnt(0)" ::: "memory");
    __builtin_amdgcn_s_barrier(); SBAR();

    // ---- layer 1: h0[64,128] x W1 (32 cols) ----
    f32x4 acc1[4][2];
    #pragma unroll
    for (int mt = 0; mt < 4; ++mt){ acc1[mt][0] = (f32x4)(b1p.x); acc1[mt][1] = (f32x4)(b1p.y); }
    #pragma unroll
    for (int ks = 0; ks < 4; ++ks){
      const unsigned cb = (unsigned)(ks*64 + lk*16);
      #pragma unroll
      for (int mt = 0; mt < 4; ++mt){
        bf16x8 a = *(const bf16x8*)&smem[HOFF + (unsigned)(mt*16 + lr) * 256 + (cb ^ xl)];
        acc1[mt][0] = __builtin_amdgcn_mfma_f32_16x16x32_bf16(a, __builtin_bit_cast(bf16x8, wf1[ks][0]), acc1[mt][0], 0, 0, 0);
        acc1[mt][1] = __builtin_amdgcn_mfma_f32_16x16x32_bf16(a, __builtin_bit_cast(bf16x8, wf1[ks][1]), acc1[mt][1], 0, 0, 0);
      }
    }

    // (4) h0 free: all L1 reads done before pd overwrites the same region
    SBAR(); asm volatile("s_waitcnt lgkmcnt(0)" ::: "memory");
    __builtin_amdgcn_s_barrier(); SBAR();

    // pd = relu(h1)*w2 (paired) -> same region as h0
    #pragma unroll
    for (int mt = 0; mt < 4; ++mt){
      #pragma unroll
      for (int r = 0; r < 4; ++r){
        float v0 = acc1[mt][0][r]; v0 = v0 > 0.f ? v0 : 0.f;
        float v1 = acc1[mt][1][r]; v1 = v1 > 0.f ? v1 : 0.f;
        float p0 = v0 * w2p.x, p1 = v1 * w2p.y;
        unsigned pk;
        asm("v_cvt_pk_bf16_f32 %0, %1, %2" : "=v"(pk) : "v"(p0), "v"(p1));
        int rr = mt*16 + lk*4 + r;
        *(unsigned*)&smem[HOFF + (unsigned)rr*256 +
            (((unsigned)(cbase*2 + 4*lr)) ^ ((unsigned)((rr & 15) << 4)))] = pk;
      }
    }

    tprev = t;
    // pd-ready enforced by next iteration's loop-top full drain + barrier
  }

  // final tile's epilogue
  SBAR(); asm volatile("s_waitcnt lgkmcnt(0)" ::: "memory");
  __builtin_amdgcn_s_barrier(); SBAR();
  if (tprev >= 0) epilogue(tprev);
}

extern "C" void kernel_launch(void* const* d_in, const int* in_sizes, int n_in,
                              void* d_out, int out_size, void* d_ws, size_t ws_size,
                              hipStream_t stream) {
  const float* zu = (const float*)d_in[0];
  const float* zm = (const float*)d_in[1];
  const int*   row = (const int*)d_in[2];
  const int*   col = (const int*)d_in[3];
  const float* W0 = (const float*)d_in[4];
  const float* b0 = (const float*)d_in[5];
  const float* W1 = (const float*)d_in[6];
  const float* b1 = (const float*)d_in[7];
  const float* W2 = (const float*)d_in[8];
  const float* b2 = (const float*)d_in[9];
  const int E = in_sizes[2];

  unsigned short* wst0 = (unsigned short*)d_ws;                       // 64 KB
  unsigned short* wst1 = wst0 + 256 * 128;                            // 32 KB
  const size_t nu = (size_t)in_sizes[0];
  const size_t nm = (size_t)in_sizes[1];
  unsigned short* zub = (unsigned short*)((char*)d_ws + 98304);
  unsigned short* zmb = zub + nu;
  const bool tab16 = ws_size >= 98304 + (nu + nm) * 2;

  hipLaunchKernelGGL(prep_weights, dim3(192), dim3(256), 0, stream, W0, W1, wst0, wst1);

  const int ntiles = (E + 63) / 64;
  const int grid = ntiles < 768 ? ntiles : 768;

  if (tab16){
    int n8u = (int)(nu / 8), n8m = (int)(nm / 8);
    hipLaunchKernelGGL(conv_bf16, dim3((n8u + 255) / 256), dim3(256), 0, stream, zu, zub, n8u);
    hipLaunchKernelGGL(conv_bf16, dim3((n8m + 255) / 256), dim3(256), 0, stream, zm, zmb, n8m);
    hipLaunchKernelGGL((edge_mlp<true>), dim3(grid), dim3(256), 0, stream,
                       zu, zm, zub, zmb, row, col, wst0, wst1, b0, b1, W2, b2,
                       (float*)d_out, E, ntiles);
  } else {
    hipLaunchKernelGGL((edge_mlp<false>), dim3(grid), dim3(256), 0, stream,
                       zu, zm, zub, zmb, row, col, wst0, wst1, b0, b1, W2, b2,
                       (float*)d_out, E, ntiles);
  }
}

// Round 16
// 394.222 us; speedup vs baseline: 1.0014x; 1.0014x over previous
//
#include <hip/hip_runtime.h>
#include <hip/hip_bf16.h>

typedef __attribute__((ext_vector_type(8))) __bf16 bf16x8;
typedef __attribute__((ext_vector_type(8))) unsigned short ushort8;
typedef __attribute__((ext_vector_type(4))) float f32x4;
typedef __attribute__((ext_vector_type(4))) unsigned uint4v;

__device__ __forceinline__ unsigned short f2bf(float f){
  union { float f; unsigned u; } v; v.f = f;
  unsigned r = v.u + 0x7fffu + ((v.u >> 16) & 1u);
  return (unsigned short)(r >> 16);
}

// non-rematerializable 16B load, SELF-WAITING: result is architecturally valid
// immediately after the asm block, so allocator spills (if any) store valid data.
__device__ __forceinline__ f32x4 gload16(const unsigned short* p){
  f32x4 r;
  asm volatile("global_load_dwordx4 %0, %1, off\n\ts_waitcnt vmcnt(0)"
               : "=v"(r) : "v"(p) : "memory");
  return r;
}

// Weight transpose+convert with per-32-col even/odd interleave:
// logical col n -> storage row nn = (n/32)*32 + (n&1)*16 + ((n%32)>>1)
__global__ void prep_weights(const float* __restrict__ W0, const float* __restrict__ W1,
                             unsigned short* __restrict__ wst0, unsigned short* __restrict__ wst1){
  int idx = blockIdx.x * 256 + threadIdx.x;
  if (idx < 256*128){
    int k = idx >> 7, n = idx & 127;
    int nn = (n >> 5) * 32 + (n & 1) * 16 + ((n & 31) >> 1);
    wst0[nn*256 + k] = f2bf(W0[idx]);
  } else if (idx < 256*128 + 128*128){
    int j = idx - 256*128;
    int k = j >> 7, n = j & 127;
    int nn = (n >> 5) * 32 + (n & 1) * 16 + ((n & 31) >> 1);
    wst1[nn*128 + k] = f2bf(W1[j]);
  }
}

__global__ void conv_bf16(const float* __restrict__ src, unsigned short* __restrict__ dst, int n8){
  int i = blockIdx.x * 256 + threadIdx.x;
  if (i < n8){
    const float4* s = (const float4*)src + (size_t)i * 2;
    float4 a = s[0], b = s[1];
    ushort8 p;
    p[0]=f2bf(a.x); p[1]=f2bf(a.y); p[2]=f2bf(a.z); p[3]=f2bf(a.w);
    p[4]=f2bf(b.x); p[5]=f2bf(b.y); p[6]=f2bf(b.z); p[7]=f2bf(b.w);
    *(ushort8*)(dst + (size_t)i * 8) = p;
  }
}

#define SBAR() __builtin_amdgcn_sched_barrier(0)

// 4 waves x 32 output cols (even/odd paired); 64 edges/tile; LDS 49152 -> 3 blocks/CU.
// amdgpu_waves_per_eu(3,3): pin allocator to 3 waves/EU -> 170-VGPR budget, no
// occupancy-chasing spills (R15: allocator chose 84 regs + 32KB/tile scratch).
template<bool TAB16>
__global__ __launch_bounds__(256) __attribute__((amdgpu_waves_per_eu(3, 3)))
void edge_mlp(
    const float* __restrict__ zu, const float* __restrict__ zm,
    const unsigned short* __restrict__ zub, const unsigned short* __restrict__ zmb,
    const int* __restrict__ row, const int* __restrict__ col,
    const unsigned short* __restrict__ wst0, const unsigned short* __restrict__ wst1,
    const float* __restrict__ b0, const float* __restrict__ b1,
    const float* __restrict__ W2, const float* __restrict__ b2v,
    float* __restrict__ out, int E, int ntiles)
{
  __shared__ unsigned char smem[49152];
  const unsigned HOFF = 32768;

  const int tid = threadIdx.x;
  const int wv = tid >> 6, lane = tid & 63;
  const int lr = lane & 15, lk = lane >> 4;
  const int cbase = wv * 32;                  // this wave's 32 logical cols
  const unsigned xl = (unsigned)(lr << 4);    // 4-bit read swizzle

  const float2 b0p = *(const float2*)(b0 + cbase + 2*lr);
  const float2 b1p = *(const float2*)(b1 + cbase + 2*lr);
  const float2 w2p = *(const float2*)(W2 + cbase + 2*lr);
  const float b2s = b2v[0];

  // per-wave weights: 24 frags = 96 VGPRs, self-waiting asm loads
  f32x4 wf0[8][2], wf1[4][2];
  #pragma unroll
  for (int ks = 0; ks < 8; ++ks){
    wf0[ks][0] = gload16(wst0 + (cbase + lr) * 256 + ks*32 + lk*8);
    wf0[ks][1] = gload16(wst0 + (cbase + 16 + lr) * 256 + ks*32 + lk*8);
  }
  #pragma unroll
  for (int ks = 0; ks < 4; ++ks){
    wf1[ks][0] = gload16(wst1 + (cbase + lr) * 128 + ks*32 + lk*8);
    wf1[ks][1] = gload16(wst1 + (cbase + 16 + lr) * 128 + ks*32 + lk*8);
  }

  int idxs[8];
  auto load_idx = [&](int tt){
    #pragma unroll
    for (int p = 0; p < 8; ++p){
      int H = p*16 + wv*4 + lk;              // half-row 0..127
      int e = tt*64 + (H >> 1); if (e >= E) e = E - 1;
      idxs[p] = (H & 1) ? col[e] : row[e];
    }
  };
  auto issue_gather = [&](){                 // direct-to-LDS, source-side 4-bit swizzle
    #pragma unroll
    for (int p = 0; p < 8; ++p){
      int H = p*16 + wv*4 + lk;
      int rl = H >> 1;                       // edge index
      const unsigned short* src = ((H & 1) ? zmb : zub)
          + (size_t)idxs[p] * 128 + ((lr ^ (rl & 15)) << 3);
      __builtin_amdgcn_global_load_lds(
          (const __attribute__((address_space(1))) unsigned*)src,
          (__attribute__((address_space(3))) unsigned*)(&smem[(unsigned)(p*16 + wv*4) * 256]),
          16, 0, 0);
    }
  };
  auto gather_f32 = [&](){                   // fallback: reg-staged convert + swizzled ds_write
    #pragma unroll
    for (int p = 0; p < 8; ++p){
      int H = p*16 + wv*4 + lk;
      int rl = H >> 1;
      const float* s = ((H & 1) ? zm : zu) + (size_t)idxs[p] * 128 + lr*8;
      float4 a = *(const float4*)s, b = *(const float4*)(s + 4);
      ushort8 pck;
      pck[0]=f2bf(a.x); pck[1]=f2bf(a.y); pck[2]=f2bf(a.z); pck[3]=f2bf(a.w);
      pck[4]=f2bf(b.x); pck[5]=f2bf(b.y); pck[6]=f2bf(b.z); pck[7]=f2bf(b.w);
      *(ushort8*)&smem[(unsigned)H * 256 + ((unsigned)(lr ^ (rl & 15)) << 4)] = pck;
    }
  };
  auto epilogue = [&](int tt){               // sum pd rows (order-invariant), 64 lanes
    if (tid < 64){
      float s = b2s;
      const unsigned rx = (unsigned)((tid & 15) << 4);
      #pragma unroll
      for (int c = 0; c < 16; ++c){
        uint4v u = *(const uint4v*)&smem[HOFF + (unsigned)tid*256 + (((unsigned)(c*16)) ^ rx)];
        #pragma unroll
        for (int j = 0; j < 4; ++j){
          union { unsigned u; float f; } lo, hi;
          lo.u = u[j] << 16; hi.u = u[j] & 0xFFFF0000u;
          s += lo.f + hi.f;
        }
      }
      int e = tt*64 + tid;
      if (e < E) out[e] = s;
    }
  };

  int t = blockIdx.x;
  int tprev = -1;
  load_idx(t);
  if constexpr (TAB16) issue_gather(); else gather_f32();

  for (; t < ntiles; t += gridDim.x){
    const int tn = t + gridDim.x;
    const bool pref = tn < ntiles;

    // (1) gather(t) ready AND pd(tprev) ready (full drain covers both)
    SBAR(); asm volatile("s_waitcnt vmcnt(0) lgkmcnt(0)" ::: "memory");
    __builtin_amdgcn_s_barrier(); SBAR();

    if (tprev >= 0) epilogue(tprev);         // hides under L0 phase
    if (pref) load_idx(tn);                  // index prefetch under L0

    // ---- layer 0: zA[64,256] x W0 (32 cols as even/odd frag pair) ----
    f32x4 acc[4][2];
    #pragma unroll
    for (int mt = 0; mt < 4; ++mt){ acc[mt][0] = (f32x4)(b0p.x); acc[mt][1] = (f32x4)(b0p.y); }
    #pragma unroll
    for (int ks = 0; ks < 8; ++ks){
      const unsigned cb = (unsigned)(ks*64 + lk*16);
      #pragma unroll
      for (int mt = 0; mt < 4; ++mt){
        bf16x8 a = *(const bf16x8*)&smem[(unsigned)(mt*16 + lr) * 512 + (cb ^ xl)];
        acc[mt][0] = __builtin_amdgcn_mfma_f32_16x16x32_bf16(a, __builtin_bit_cast(bf16x8, wf0[ks][0]), acc[mt][0], 0, 0, 0);
        acc[mt][1] = __builtin_amdgcn_mfma_f32_16x16x32_bf16(a, __builtin_bit_cast(bf16x8, wf0[ks][1]), acc[mt][1], 0, 0, 0);
      }
    }

    // (2) zA free (and epilogue reads done before h0-write overwrites region)
    SBAR(); asm volatile("s_waitcnt lgkmcnt(0)" ::: "memory");
    __builtin_amdgcn_s_barrier(); SBAR();

    if (pref){ if constexpr (TAB16) issue_gather(); else gather_f32(); }  // flies to next loop-top

    // h0 = relu(acc) -> LDS, paired cols -> one b32 write per (mt,r); 2-way max
    #pragma unroll
    for (int mt = 0; mt < 4; ++mt){
      #pragma unroll
      for (int r = 0; r < 4; ++r){
        float v0 = acc[mt][0][r]; v0 = v0 > 0.f ? v0 : 0.f;
        float v1 = acc[mt][1][r]; v1 = v1 > 0.f ? v1 : 0.f;
        unsigned pk;
        asm("v_cvt_pk_bf16_f32 %0, %1, %2" : "=v"(pk) : "v"(v0), "v"(v1));
        int rr = mt*16 + lk*4 + r;
        *(unsigned*)&smem[HOFF + (unsigned)rr*256 +
            (((unsigned)(cbase*2 + 4*lr)) ^ ((unsigned)((rr & 15) << 4)))] = pk;
      }
    }

    // (3) h0 ready
    SBAR(); asm volatile("s_waitcnt lgkmcnt(0)" ::: "memory");
    __builtin_amdgcn_s_barrier(); SBAR();

    // ---- layer 1: h0[64,128] x W1 (32 cols) ----
    f32x4 acc1[4][2];
    #pragma unroll
    for (int mt = 0; mt < 4; ++mt){ acc1[mt][0] = (f32x4)(b1p.x); acc1[mt][1] = (f32x4)(b1p.y); }
    #pragma unroll
    for (int ks = 0; ks < 4; ++ks){
      const unsigned cb = (unsigned)(ks*64 + lk*16);
      #pragma unroll
      for (int mt = 0; mt < 4; ++mt){
        bf16x8 a = *(const bf16x8*)&smem[HOFF + (unsigned)(mt*16 + lr) * 256 + (cb ^ xl)];
        acc1[mt][0] = __builtin_amdgcn_mfma_f32_16x16x32_bf16(a, __builtin_bit_cast(bf16x8, wf1[ks][0]), acc1[mt][0], 0, 0, 0);
        acc1[mt][1] = __builtin_amdgcn_mfma_f32_16x16x32_bf16(a, __builtin_bit_cast(bf16x8, wf1[ks][1]), acc1[mt][1], 0, 0, 0);
      }
    }

    // (4) h0 free: all L1 reads done before pd overwrites the same region
    SBAR(); asm volatile("s_waitcnt lgkmcnt(0)" ::: "memory");
    __builtin_amdgcn_s_barrier(); SBAR();

    // pd = relu(h1)*w2 (paired) -> same region as h0
    #pragma unroll
    for (int mt = 0; mt < 4; ++mt){
      #pragma unroll
      for (int r = 0; r < 4; ++r){
        float v0 = acc1[mt][0][r]; v0 = v0 > 0.f ? v0 : 0.f;
        float v1 = acc1[mt][1][r]; v1 = v1 > 0.f ? v1 : 0.f;
        float p0 = v0 * w2p.x, p1 = v1 * w2p.y;
        unsigned pk;
        asm("v_cvt_pk_bf16_f32 %0, %1, %2" : "=v"(pk) : "v"(p0), "v"(p1));
        int rr = mt*16 + lk*4 + r;
        *(unsigned*)&smem[HOFF + (unsigned)rr*256 +
            (((unsigned)(cbase*2 + 4*lr)) ^ ((unsigned)((rr & 15) << 4)))] = pk;
      }
    }

    tprev = t;
    // pd-ready enforced by next iteration's loop-top full drain + barrier
  }

  // final tile's epilogue
  SBAR(); asm volatile("s_waitcnt lgkmcnt(0)" ::: "memory");
  __builtin_amdgcn_s_barrier(); SBAR();
  if (tprev >= 0) epilogue(tprev);
}

extern "C" void kernel_launch(void* const* d_in, const int* in_sizes, int n_in,
                              void* d_out, int out_size, void* d_ws, size_t ws_size,
                              hipStream_t stream) {
  const float* zu = (const float*)d_in[0];
  const float* zm = (const float*)d_in[1];
  const int*   row = (const int*)d_in[2];
  const int*   col = (const int*)d_in[3];
  const float* W0 = (const float*)d_in[4];
  const float* b0 = (const float*)d_in[5];
  const float* W1 = (const float*)d_in[6];
  const float* b1 = (const float*)d_in[7];
  const float* W2 = (const float*)d_in[8];
  const float* b2 = (const float*)d_in[9];
  const int E = in_sizes[2];

  unsigned short* wst0 = (unsigned short*)d_ws;                       // 64 KB
  unsigned short* wst1 = wst0 + 256 * 128;                            // 32 KB
  const size_t nu = (size_t)in_sizes[0];
  const size_t nm = (size_t)in_sizes[1];
  unsigned short* zub = (unsigned short*)((char*)d_ws + 98304);
  unsigned short* zmb = zub + nu;
  const bool tab16 = ws_size >= 98304 + (nu + nm) * 2;

  hipLaunchKernelGGL(prep_weights, dim3(192), dim3(256), 0, stream, W0, W1, wst0, wst1);

  const int ntiles = (E + 63) / 64;
  const int grid = ntiles < 768 ? ntiles : 768;

  if (tab16){
    int n8u = (int)(nu / 8), n8m = (int)(nm / 8);
    hipLaunchKernelGGL(conv_bf16, dim3((n8u + 255) / 256), dim3(256), 0, stream, zu, zub, n8u);
    hipLaunchKernelGGL(conv_bf16, dim3((n8m + 255) / 256), dim3(256), 0, stream, zm, zmb, n8m);
    hipLaunchKernelGGL((edge_mlp<true>), dim3(grid), dim3(256), 0, stream,
                       zu, zm, zub, zmb, row, col, wst0, wst1, b0, b1, W2, b2,
                       (float*)d_out, E, ntiles);
  } else {
    hipLaunchKernelGGL((edge_mlp<false>), dim3(grid), dim3(256), 0, stream,
                       zu, zm, zub, zmb, row, col, wst0, wst1, b0, b1, W2, b2,
                       (float*)d_out, E, ntiles);
  }
}

// Round 17
// 189.314 us; speedup vs baseline: 2.0854x; 2.0824x over previous
//
#include <hip/hip_runtime.h>
#include <hip/hip_bf16.h>

typedef __attribute__((ext_vector_type(8))) __bf16 bf16x8;
typedef __attribute__((ext_vector_type(8))) unsigned short ushort8;
typedef __attribute__((ext_vector_type(4))) float f32x4;
typedef __attribute__((ext_vector_type(4))) unsigned uint4v;

__device__ __forceinline__ unsigned short f2bf(float f){
  union { float f; unsigned u; } v; v.f = f;
  unsigned r = v.u + 0x7fffu + ((v.u >> 16) & 1u);
  return (unsigned short)(r >> 16);
}

// non-rematerializable 16B load (self-waiting; safe under spills)
__device__ __forceinline__ f32x4 gload16(const unsigned short* p){
  f32x4 r;
  asm volatile("global_load_dwordx4 %0, %1, off\n\ts_waitcnt vmcnt(0)"
               : "=v"(r) : "v"(p) : "memory");
  return r;
}

// Plain transpose+convert: wst0[n][k] = bf16(W0[k][n]) (128x256), wst1 likewise (128x128)
__global__ void prep_weights(const float* __restrict__ W0, const float* __restrict__ W1,
                             unsigned short* __restrict__ wst0, unsigned short* __restrict__ wst1){
  int idx = blockIdx.x * 256 + threadIdx.x;
  if (idx < 256*128){
    int k = idx >> 7, n = idx & 127;
    wst0[n*256 + k] = f2bf(W0[idx]);
  } else if (idx < 256*128 + 128*128){
    int j = idx - 256*128;
    int k = j >> 7, n = j & 127;
    wst1[n*128 + k] = f2bf(W1[j]);
  }
}

__global__ void conv_bf16(const float* __restrict__ src, unsigned short* __restrict__ dst, int n8){
  int i = blockIdx.x * 256 + threadIdx.x;
  if (i < n8){
    const float4* s = (const float4*)src + (size_t)i * 2;
    float4 a = s[0], b = s[1];
    ushort8 p;
    p[0]=f2bf(a.x); p[1]=f2bf(a.y); p[2]=f2bf(a.z); p[3]=f2bf(a.w);
    p[4]=f2bf(b.x); p[5]=f2bf(b.y); p[6]=f2bf(b.z); p[7]=f2bf(b.w);
    *(ushort8*)(dst + (size_t)i * 8) = p;
  }
}

#define SBAR() __builtin_amdgcn_sched_barrier(0)

// R10 layout, 3-barrier loop: 8 waves x 16 cols; 64 edges/tile; LDS 65536 -> 2 blocks/CU.
//   zA:    [0,32768)      128 half-rows x 256B, chunk ^ (edge&15) (source-side)
//   h0:    [32768,49152)  64 rows x 256B bf16, byte ^ ((row&15)<<4)
//   pdbuf: [49152,65536)  64 rows x 128 cols bf16, byte ^ ((row&15)<<4)
// epilogue(t) deferred into tile t+1's L0 phase (loop-top full drain = pd ready);
// the pd-ready barrier of R10 is deleted. Safety: epilogue reads end before wave0
// passes barrier(2); all pd-writes occur after barrier(3) > barrier(2).
template<bool TAB16>
__global__ __launch_bounds__(512, 4) void edge_mlp(
    const float* __restrict__ zu, const float* __restrict__ zm,
    const unsigned short* __restrict__ zub, const unsigned short* __restrict__ zmb,
    const int* __restrict__ row, const int* __restrict__ col,
    const unsigned short* __restrict__ wst0, const unsigned short* __restrict__ wst1,
    const float* __restrict__ b0, const float* __restrict__ b1,
    const float* __restrict__ W2, const float* __restrict__ b2v,
    float* __restrict__ out, int E, int ntiles)
{
  __shared__ unsigned char smem[65536];
  const unsigned HOFF = 32768, POFF = 49152;

  const int tid = threadIdx.x;
  const int wv = tid >> 6, lane = tid & 63;
  const int lr = lane & 15, lk = lane >> 4;
  const int ncol = wv * 16;                   // this wave's 16 output cols
  const unsigned xl = (unsigned)(lr << 4);    // 4-bit read swizzle

  const float b0s = b0[ncol + lr];
  const float b1s = b1[ncol + lr];
  const float w2s = W2[ncol + lr];
  const float b2s = b2v[0];

  // per-wave weights: 12 frags = 48 VGPRs (proven resident at VGPR=64)
  f32x4 wf[12];
  #pragma unroll
  for (int ks = 0; ks < 8; ++ks)
    wf[ks] = gload16(wst0 + (ncol + lr) * 256 + ks*32 + lk*8);
  #pragma unroll
  for (int ks = 0; ks < 4; ++ks)
    wf[8+ks] = gload16(wst1 + (ncol + lr) * 128 + ks*32 + lk*8);

  int idxs[4];
  auto load_idx = [&](int tt){
    #pragma unroll
    for (int p = 0; p < 4; ++p){
      int H = p*32 + wv*4 + lk;              // half-row 0..127
      int e = tt*64 + (H >> 1); if (e >= E) e = E - 1;
      idxs[p] = (H & 1) ? col[e] : row[e];
    }
  };
  auto issue_gather = [&](){                 // direct-to-LDS, source-side 4-bit swizzle
    #pragma unroll
    for (int p = 0; p < 4; ++p){
      int H = p*32 + wv*4 + lk;
      int rl = H >> 1;                       // edge index
      const unsigned short* src = ((H & 1) ? zmb : zub)
          + (size_t)idxs[p] * 128 + ((lr ^ (rl & 15)) << 3);
      __builtin_amdgcn_global_load_lds(
          (const __attribute__((address_space(1))) unsigned*)src,
          (__attribute__((address_space(3))) unsigned*)(&smem[(unsigned)(p*32 + wv*4) * 256]),
          16, 0, 0);
    }
  };
  auto gather_f32 = [&](){                   // fallback: reg-staged convert + swizzled ds_write
    #pragma unroll
    for (int p = 0; p < 4; ++p){
      int H = p*32 + wv*4 + lk;
      int rl = H >> 1;
      const float* s = ((H & 1) ? zm : zu) + (size_t)idxs[p] * 128 + lr*8;
      float4 a = *(const float4*)s, b = *(const float4*)(s + 4);
      ushort8 pck;
      pck[0]=f2bf(a.x); pck[1]=f2bf(a.y); pck[2]=f2bf(a.z); pck[3]=f2bf(a.w);
      pck[4]=f2bf(b.x); pck[5]=f2bf(b.y); pck[6]=f2bf(b.z); pck[7]=f2bf(b.w);
      *(ushort8*)&smem[(unsigned)H * 256 + ((unsigned)(lr ^ (rl & 15)) << 4)] = pck;
    }
  };
  auto epilogue = [&](int tt){               // sum pdbuf rows (order-invariant), 64 lanes
    if (tid < 64){
      float s = b2s;
      const unsigned rx = (unsigned)((tid & 15) << 4);
      #pragma unroll
      for (int c = 0; c < 16; ++c){
        uint4v u = *(const uint4v*)&smem[POFF + (unsigned)tid*256 + (((unsigned)(c*16)) ^ rx)];
        #pragma unroll
        for (int j = 0; j < 4; ++j){
          union { unsigned u; float f; } lo, hi;
          lo.u = u[j] << 16; hi.u = u[j] & 0xFFFF0000u;
          s += lo.f + hi.f;
        }
      }
      int e = tt*64 + tid;
      if (e < E) out[e] = s;
    }
  };

  int t = blockIdx.x;
  int tprev = -1;
  load_idx(t);
  if constexpr (TAB16) issue_gather(); else gather_f32();

  for (; t < ntiles; t += gridDim.x){
    const int tn = t + gridDim.x;
    const bool pref = tn < ntiles;

    // (1) gather(t) ready AND pd(tprev) complete (full drain + barrier)
    SBAR(); asm volatile("s_waitcnt vmcnt(0) lgkmcnt(0)" ::: "memory");
    __builtin_amdgcn_s_barrier(); SBAR();

    if (tprev >= 0) epilogue(tprev);         // wave 0 only; hides under L0
    if (pref) load_idx(tn);                  // index prefetch under L0

    // ---- layer 0: zA[64,256] x W0 (16 cols) ----
    f32x4 acc0[4];
    #pragma unroll
    for (int mt = 0; mt < 4; ++mt) acc0[mt] = (f32x4)(b0s);
    #pragma unroll
    for (int ks = 0; ks < 8; ++ks){
      const unsigned cb = (unsigned)(ks*64 + lk*16);
      #pragma unroll
      for (int mt = 0; mt < 4; ++mt){
        bf16x8 a = *(const bf16x8*)&smem[(unsigned)(mt*16 + lr) * 512 + (cb ^ xl)];
        acc0[mt] = __builtin_amdgcn_mfma_f32_16x16x32_bf16(a, __builtin_bit_cast(bf16x8, wf[ks]), acc0[mt], 0, 0, 0);
      }
    }

    // (2) zA free (wave0 epilogue reads also complete: program order before this)
    SBAR(); asm volatile("s_waitcnt lgkmcnt(0)" ::: "memory");
    __builtin_amdgcn_s_barrier(); SBAR();

    if (pref){ if constexpr (TAB16) issue_gather(); else gather_f32(); }  // flies to next loop-top

    // h0 = relu(acc0) -> LDS (b16 stores, 4-bit row-XOR -> 2-way max)
    #pragma unroll
    for (int mt = 0; mt < 4; ++mt){
      #pragma unroll
      for (int r = 0; r < 4; ++r){
        float v = acc0[mt][r]; v = v > 0.f ? v : 0.f;
        int rr = mt*16 + lk*4 + r;
        *(unsigned short*)&smem[HOFF + (unsigned)rr*256 +
            (((unsigned)((ncol + lr)*2)) ^ ((unsigned)((rr & 15) << 4)))] = f2bf(v);
      }
    }

    // (3) h0 ready
    SBAR(); asm volatile("s_waitcnt lgkmcnt(0)" ::: "memory");
    __builtin_amdgcn_s_barrier(); SBAR();

    // ---- layer 1: h0[64,128] x W1 (16 cols) ----
    f32x4 acc1[4];
    #pragma unroll
    for (int mt = 0; mt < 4; ++mt) acc1[mt] = (f32x4)(b1s);
    #pragma unroll
    for (int ks = 0; ks < 4; ++ks){
      const unsigned cb = (unsigned)(ks*64 + lk*16);
      #pragma unroll
      for (int mt = 0; mt < 4; ++mt){
        bf16x8 a = *(const bf16x8*)&smem[HOFF + (unsigned)(mt*16 + lr) * 256 + (cb ^ xl)];
        acc1[mt] = __builtin_amdgcn_mfma_f32_16x16x32_bf16(a, __builtin_bit_cast(bf16x8, wf[8+ks]), acc1[mt], 0, 0, 0);
      }
    }

    // pd = relu(h1)*w2 -> pdbuf (separate region; epilogue(t) deferred to next iter)
    #pragma unroll
    for (int mt = 0; mt < 4; ++mt){
      #pragma unroll
      for (int r = 0; r < 4; ++r){
        float v = acc1[mt][r]; v = v > 0.f ? v : 0.f;
        int rr = mt*16 + lk*4 + r;
        *(unsigned short*)&smem[POFF + (unsigned)rr*256 +
            (((unsigned)((ncol + lr)*2)) ^ ((unsigned)((rr & 15) << 4)))] = f2bf(v * w2s);
      }
    }

    tprev = t;
    // no pd-ready barrier: next loop-top full drain + barrier covers it
  }

  // final tile's epilogue
  SBAR(); asm volatile("s_waitcnt lgkmcnt(0)" ::: "memory");
  __builtin_amdgcn_s_barrier(); SBAR();
  if (tprev >= 0) epilogue(tprev);
}

extern "C" void kernel_launch(void* const* d_in, const int* in_sizes, int n_in,
                              void* d_out, int out_size, void* d_ws, size_t ws_size,
                              hipStream_t stream) {
  const float* zu = (const float*)d_in[0];
  const float* zm = (const float*)d_in[1];
  const int*   row = (const int*)d_in[2];
  const int*   col = (const int*)d_in[3];
  const float* W0 = (const float*)d_in[4];
  const float* b0 = (const float*)d_in[5];
  const float* W1 = (const float*)d_in[6];
  const float* b1 = (const float*)d_in[7];
  const float* W2 = (const float*)d_in[8];
  const float* b2 = (const float*)d_in[9];
  const int E = in_sizes[2];

  unsigned short* wst0 = (unsigned short*)d_ws;                       // 64 KB
  unsigned short* wst1 = wst0 + 256 * 128;                            // 32 KB
  const size_t nu = (size_t)in_sizes[0];
  const size_t nm = (size_t)in_sizes[1];
  unsigned short* zub = (unsigned short*)((char*)d_ws + 98304);
  unsigned short* zmb = zub + nu;
  const bool tab16 = ws_size >= 98304 + (nu + nm) * 2;

  hipLaunchKernelGGL(prep_weights, dim3(192), dim3(256), 0, stream, W0, W1, wst0, wst1);

  const int ntiles = (E + 63) / 64;
  const int grid = ntiles < 512 ? ntiles : 512;

  if (tab16){
    int n8u = (int)(nu / 8), n8m = (int)(nm / 8);
    hipLaunchKernelGGL(conv_bf16, dim3((n8u + 255) / 256), dim3(256), 0, stream, zu, zub, n8u);
    hipLaunchKernelGGL(conv_bf16, dim3((n8m + 255) / 256), dim3(256), 0, stream, zm, zmb, n8m);
    hipLaunchKernelGGL((edge_mlp<true>), dim3(grid), dim3(512), 0, stream,
                       zu, zm, zub, zmb, row, col, wst0, wst1, b0, b1, W2, b2,
                       (float*)d_out, E, ntiles);
  } else {
    hipLaunchKernelGGL((edge_mlp<false>), dim3(grid), dim3(512), 0, stream,
                       zu, zm, zub, zmb, row, col, wst0, wst1, b0, b1, W2, b2,
                       (float*)d_out, E, ntiles);
  }
}